// Round 10
// baseline (326.412 us; speedup 1.0000x reference)
//
#include <hip/hip_runtime.h>
#include <hip/hip_fp16.h>

// SpatialAwareAttention — round 10: round-9 + double-buffered 4-plane GEMM.
// mfma_gemm: 24 fat steps (48 MFMA/wave) x 2-phase prefetch (STAGE next ->
// buf^1 issued BEFORE compute on buf; ONE barrier/step so the vmcnt drain
// lands after the compute window). LDS 64KB -> 2 blocks/CU (= grid's 2.25).
// attn v3 (fixed-base softmax, u32-packed P), bias_mlp v2, splits unchanged.

typedef unsigned short ushort_t;
typedef unsigned int uint_t;
typedef __attribute__((ext_vector_type(8))) short bf16x8;
typedef __attribute__((ext_vector_type(4))) float f32x4;

__device__ __forceinline__ ushort_t f2b(float f) {  // fp32 -> bf16 (RNE)
    union { float f; uint_t u; } v;
    v.f = f;
    uint_t r = v.u + 0x7fffu + ((v.u >> 16) & 1u);
    return (ushort_t)(r >> 16);
}
__device__ __forceinline__ float b2f(ushort_t b) {
    union { uint_t u; float f; } v;
    v.u = ((uint_t)b) << 16;
    return v.f;
}

__device__ __forceinline__ void gload16(const void* g, void* l) {
    __builtin_amdgcn_global_load_lds(
        (const __attribute__((address_space(1))) unsigned int*)g,
        (__attribute__((address_space(3))) unsigned int*)l, 16, 0, 0);
}

// ---------------------------------------------------------------------------
// X[4096][768] fp32 -> X2[4096][1536] bf16 as [hi | lo]
// ---------------------------------------------------------------------------
__global__ __launch_bounds__(256) void split_hi_lo(const float* __restrict__ X,
                                                   ushort_t* __restrict__ X2) {
    const int idx = blockIdx.x * 256 + threadIdx.x;
    const int m = idx / 192, k4 = (idx - m * 192) * 4;
    float4 v = *(const float4*)&X[(size_t)m * 768 + k4];
    ushort4 hi, lo;
    hi.x = f2b(v.x); lo.x = f2b(v.x - b2f(hi.x));
    hi.y = f2b(v.y); lo.y = f2b(v.y - b2f(hi.y));
    hi.z = f2b(v.z); lo.z = f2b(v.z - b2f(hi.z));
    hi.w = f2b(v.w); lo.w = f2b(v.w - b2f(hi.w));
    ushort_t* row = X2 + (size_t)m * 1536;
    *(ushort4*)&row[k4]       = hi;
    *(ushort4*)&row[768 + k4] = lo;
}

// ---------------------------------------------------------------------------
// W[768 k][768 n] fp32 -> Wt[n_base+n][1536] bf16 as [hi | lo] along k
// ---------------------------------------------------------------------------
__global__ __launch_bounds__(256) void split_wT(const float* __restrict__ W,
                                                ushort_t* __restrict__ Wt,
                                                int n_base) {
    __shared__ float Ws[64][65];
    const int t = threadIdx.x;
    const int rr0 = blockIdx.x * 64, nn0 = blockIdx.y * 64;
    const int c = t & 63, r4 = t >> 6;
#pragma unroll
    for (int e = 0; e < 16; ++e) {
        const int r = r4 + e * 4;
        Ws[r][c] = W[(size_t)(rr0 + r) * 768 + nn0 + c];
    }
    __syncthreads();
#pragma unroll
    for (int e = 0; e < 16; ++e) {
        const int nloc = r4 + e * 4;
        const float v = Ws[c][nloc];
        const ushort_t h = f2b(v);
        const ushort_t l = f2b(v - b2f(h));
        ushort_t* rowp = Wt + (size_t)(n_base + nn0 + nloc) * 1536 + rr0 + c;
        rowp[0]   = h;
        rowp[768] = l;
    }
}

// ---------------------------------------------------------------------------
// W2[32][12] -> W2t[12][32] fp32
// ---------------------------------------------------------------------------
__global__ __launch_bounds__(384) void prep_w2t(const float* __restrict__ W2,
                                                float* __restrict__ W2t) {
    const int t = threadIdx.x;
    const int h = t >> 5, u = t & 31;
    W2t[t] = W2[u * 12 + h];
}

// ---------------------------------------------------------------------------
// GEMM: C[4096 x N] = A @ W  (bf16x3: AhWh + AhWl + AlWh).
// 128x128 tile, BK=32, 4 co-staged planes {Ah,Al,Wh,Wl}, DOUBLE-buffered
// (2 x 32KB), 24 steps x 48 MFMA/wave, one barrier per step.
// ---------------------------------------------------------------------------
template <int QKV>
__global__ __launch_bounds__(256) void mfma_gemm(
    const ushort_t* __restrict__ A2, const ushort_t* __restrict__ Bt,
    const float* __restrict__ bv0, const float* __restrict__ bv1,
    const float* __restrict__ bv2, ushort_t* __restrict__ Qh,
    ushort_t* __restrict__ Ql, ushort_t* __restrict__ Kh,
    ushort_t* __restrict__ Kl, ushort_t* __restrict__ Vth,
    ushort_t* __restrict__ Vtl, float* __restrict__ C0) {
    __shared__ ushort_t Ls[2][4][128 * 32];   // [buf][plane 0=Ah 1=Al 2=Wh 3=Wl]

    const int t = threadIdx.x;
    const int w = t >> 6, lane = t & 63;
    const int lm = lane & 15, l4 = lane >> 4;

    const int nbx = QKV ? 18 : 6;
    const int lid0 = blockIdx.y * nbx + blockIdx.x;
    const int cpx = (nbx * 32) >> 3;
    const int lid = (lid0 & 7) * cpx + (lid0 >> 3);
    const int n0 = (lid % nbx) * 128;
    const int m0 = (lid / nbx) * 128;

    const int wr = (w >> 1) * 64, wc = (w & 1) * 64;

    f32x4 acc[4][4];
#pragma unroll
    for (int i = 0; i < 4; ++i)
#pragma unroll
        for (int j = 0; j < 4; ++j) acc[i][j] = (f32x4){0.f, 0.f, 0.f, 0.f};

    const int sr0 = t >> 2, ss0 = t & 3;
    const int sr1 = (t + 256) >> 2, ss1 = (t + 256) & 3;
    const int k80 = (ss0 ^ ((sr0 >> 1) & 3)) << 3;
    const int k81 = (ss1 ^ ((sr1 >> 1) & 3)) << 3;

    const ushort_t* baseA = A2 + (size_t)m0 * 1536;
    const ushort_t* baseB = Bt + (size_t)n0 * 1536;

    auto STAGE = [&](int buf, int k0) {
        gload16(baseA + (size_t)sr0 * 1536 + k0 + k80, (char*)&Ls[buf][0][0] + t * 16);
        gload16(baseA + (size_t)sr1 * 1536 + k0 + k81,
                (char*)&Ls[buf][0][0] + (t + 256) * 16);
        gload16(baseA + (size_t)sr0 * 1536 + 768 + k0 + k80,
                (char*)&Ls[buf][1][0] + t * 16);
        gload16(baseA + (size_t)sr1 * 1536 + 768 + k0 + k81,
                (char*)&Ls[buf][1][0] + (t + 256) * 16);
        gload16(baseB + (size_t)sr0 * 1536 + k0 + k80, (char*)&Ls[buf][2][0] + t * 16);
        gload16(baseB + (size_t)sr1 * 1536 + k0 + k81,
                (char*)&Ls[buf][2][0] + (t + 256) * 16);
        gload16(baseB + (size_t)sr0 * 1536 + 768 + k0 + k80,
                (char*)&Ls[buf][3][0] + t * 16);
        gload16(baseB + (size_t)sr1 * 1536 + 768 + k0 + k81,
                (char*)&Ls[buf][3][0] + (t + 256) * 16);
    };

    auto COMPUTE = [&](int buf) {
        bf16x8 ah[4], al[4];
#pragma unroll
        for (int i = 0; i < 4; ++i) {
            const int ra = wr + i * 16 + lm;
            const int sa = (l4 ^ ((ra >> 1) & 3)) << 4;
            ah[i] = *(const bf16x8*)((const char*)&Ls[buf][0][0] + ra * 64 + sa);
            al[i] = *(const bf16x8*)((const char*)&Ls[buf][1][0] + ra * 64 + sa);
        }
#pragma unroll
        for (int j = 0; j < 4; ++j) {
            const int rb = wc + j * 16 + lm;
            const int sb = (l4 ^ ((rb >> 1) & 3)) << 4;
            const bf16x8 bh =
                *(const bf16x8*)((const char*)&Ls[buf][2][0] + rb * 64 + sb);
            const bf16x8 bl =
                *(const bf16x8*)((const char*)&Ls[buf][3][0] + rb * 64 + sb);
#pragma unroll
            for (int i = 0; i < 4; ++i) {
                acc[i][j] = __builtin_amdgcn_mfma_f32_16x16x32_bf16(ah[i], bh,
                                                                    acc[i][j], 0, 0, 0);
                acc[i][j] = __builtin_amdgcn_mfma_f32_16x16x32_bf16(ah[i], bl,
                                                                    acc[i][j], 0, 0, 0);
                acc[i][j] = __builtin_amdgcn_mfma_f32_16x16x32_bf16(al[i], bh,
                                                                    acc[i][j], 0, 0, 0);
            }
        }
    };

    STAGE(0, 0);
    __syncthreads();
    for (int q = 0; q < 24; ++q) {
        const int cur = q & 1;
        if (q + 1 < 24) STAGE(cur ^ 1, (q + 1) * 32);  // loads fly under compute
        COMPUTE(cur);
        __syncthreads();  // one barrier/step: drains new loads + this buf's reads
    }

    const int cl = lane & 15, rg = (lane >> 4) * 4;
    if constexpr (QKV) {
        const int which = n0 / 768;
        const int nb = n0 - which * 768 + wc;
        const float* bb = which == 0 ? bv0 : (which == 1 ? bv1 : bv2);
#pragma unroll
        for (int i = 0; i < 4; ++i)
#pragma unroll
            for (int j = 0; j < 4; ++j) {
                const int cw = nb + j * 16 + cl;
                const int h = cw >> 6, d = cw & 63;
                const float badd = bb[cw];
#pragma unroll
                for (int r = 0; r < 4; ++r) {
                    const int gr = m0 + wr + i * 16 + rg + r;
                    const int b = gr >> 10, l = gr & 1023;
                    const int bh2 = b * 12 + h;
                    float val = acc[i][j][r] + badd;
                    if (which == 0) val *= 0.125f;
                    const ushort_t hi = f2b(val);
                    const ushort_t lo = f2b(val - b2f(hi));
                    if (which == 0) {
                        const size_t idx = ((size_t)((bh2 << 10) + l)) * 64 + d;
                        Qh[idx] = hi; Ql[idx] = lo;
                    } else if (which == 1) {
                        const size_t idx = ((size_t)((bh2 << 10) + l)) * 64 + d;
                        Kh[idx] = hi; Kl[idx] = lo;
                    } else {
                        const size_t idx = (((size_t)((bh2 << 6) + d)) << 10) + l;
                        Vth[idx] = hi; Vtl[idx] = lo;
                    }
                }
            }
    } else {
#pragma unroll
        for (int i = 0; i < 4; ++i)
#pragma unroll
            for (int j = 0; j < 4; ++j) {
                const int gc = n0 + wc + j * 16 + cl;
#pragma unroll
                for (int r = 0; r < 4; ++r) {
                    const int gr = m0 + wr + i * 16 + rg + r;
                    C0[(size_t)gr * 768 + gc] = acc[i][j][r] + bv0[gc];
                }
            }
    }
}

// ---------------------------------------------------------------------------
// bias[b][h][i][j] = relu(delta@W1+b1)@W2[:,h] + b2[h] - 12  -> fp16
// (-12 = fixed softmax base; softmax is shift-invariant). SGPR weight loads.
// ---------------------------------------------------------------------------
__global__ __launch_bounds__(256) void bias_mlp(const float* __restrict__ pos,
                                                const float* __restrict__ W1,
                                                const float* __restrict__ b1,
                                                const float* __restrict__ W2t,
                                                const float* __restrict__ b2,
                                                __half* __restrict__ Bias) {
    const int t = threadIdx.x;
    const int i = blockIdx.x;
    const int b = blockIdx.y;
    const int j0 = blockIdx.z * 512;

    const float2 pi2 = *(const float2*)&pos[((b << 10) + i) << 1];
    const float4 pj01 = *(const float4*)&pos[((b << 10) + j0 + 2 * t) << 1];
    float dx[2], dy[2];
    dx[0] = pi2.x - pj01.x; dy[0] = pi2.y - pj01.y;
    dx[1] = pi2.x - pj01.z; dy[1] = pi2.y - pj01.w;

    float acc[2][12];
#pragma unroll
    for (int h = 0; h < 12; ++h) {
        const float bb = b2[h] - 12.f;
        acc[0][h] = bb;
        acc[1][h] = bb;
    }

    for (int u4 = 0; u4 < 8; ++u4) {
        const float4 ax = *(const float4*)&W1[u4 * 4];
        const float4 ay = *(const float4*)&W1[32 + u4 * 4];
        const float4 ab = *(const float4*)&b1[u4 * 4];
        float4 hv[2];
#pragma unroll
        for (int e = 0; e < 2; ++e) {
            hv[e].x = fmaxf(fmaf(dx[e], ax.x, fmaf(dy[e], ay.x, ab.x)), 0.f);
            hv[e].y = fmaxf(fmaf(dx[e], ax.y, fmaf(dy[e], ay.y, ab.y)), 0.f);
            hv[e].z = fmaxf(fmaf(dx[e], ax.z, fmaf(dy[e], ay.z, ab.z)), 0.f);
            hv[e].w = fmaxf(fmaf(dx[e], ax.w, fmaf(dy[e], ay.w, ab.w)), 0.f);
        }
#pragma unroll
        for (int h = 0; h < 12; ++h) {
            const float4 wv = *(const float4*)&W2t[h * 32 + u4 * 4];
#pragma unroll
            for (int e = 0; e < 2; ++e)
                acc[e][h] = fmaf(hv[e].x, wv.x,
                            fmaf(hv[e].y, wv.y,
                            fmaf(hv[e].z, wv.z,
                            fmaf(hv[e].w, wv.w, acc[e][h]))));
        }
    }

    const size_t base = (((size_t)(b * 12)) << 20) + (((size_t)i) << 10) + j0;
#pragma unroll
    for (int h = 0; h < 12; ++h)
        *(__half2*)&Bias[base + (((size_t)h) << 20) + 2 * t] =
            __floats2half2_rn(acc[0][h], acc[1][h]);
}

// ---------------------------------------------------------------------------
// MFMA flash attention v3 (unchanged from round 9).
// ---------------------------------------------------------------------------
__global__ __launch_bounds__(128) void attn_mfma(
    const ushort_t* __restrict__ Qh, const ushort_t* __restrict__ Ql,
    const ushort_t* __restrict__ Kh, const ushort_t* __restrict__ Kl,
    const ushort_t* __restrict__ Vth, const ushort_t* __restrict__ Vtl,
    const __half* __restrict__ BiasT, ushort_t* __restrict__ A2) {
    __shared__ ushort_t Kls[2][64][64];
    __shared__ ushort_t Vls[2][64][64];
    __shared__ __align__(16) uint_t P32[2][2][16][64];

    const int t = threadIdx.x;
    const int wgid0 = blockIdx.x;
    const int wgid = (wgid0 & 7) * 96 + (wgid0 >> 3);
    const int bh = wgid >> 4, it = wgid & 15;
    const int b = bh / 12, h = bh - b * 12;
    const int i0 = it << 6;
    const int w = t >> 6, l = t & 63;
    const int l4 = l >> 4, lm = l & 15;
    const int rowbase = i0 + 32 * w;

    const __half* bpb = BiasT + (((size_t)bh) << 20) +
                        (((size_t)(rowbase + l4 * 4)) << 10) + lm;

    bf16x8 qh_[2][2], ql_[2][2];
#pragma unroll
    for (int rg = 0; rg < 2; ++rg) {
        const size_t qoff =
            ((size_t)((bh << 10) + rowbase + rg * 16 + lm)) * 64 + l4 * 8;
        qh_[rg][0] = *(const bf16x8*)(Qh + qoff);
        qh_[rg][1] = *(const bf16x8*)(Qh + qoff + 32);
        ql_[rg][0] = *(const bf16x8*)(Ql + qoff);
        ql_[rg][1] = *(const bf16x8*)(Ql + qoff + 32);
    }

    float lsum[2][4];
    f32x4 o_[2][4];
#pragma unroll
    for (int rg = 0; rg < 2; ++rg)
#pragma unroll
        for (int r = 0; r < 4; ++r) {
            lsum[rg][r] = 0.f;
            o_[rg][r] = (f32x4){0.f, 0.f, 0.f, 0.f};
        }

    for (int jt = 0; jt < 16; ++jt) {
        const int j0 = jt << 6;

        float bias_r[2][4][4];
#pragma unroll
        for (int rg = 0; rg < 2; ++rg)
#pragma unroll
            for (int cb = 0; cb < 4; ++cb)
#pragma unroll
                for (int r = 0; r < 4; ++r)
                    bias_r[rg][cb][r] = __half2float(
                        bpb[((rg * 16 + r) << 10) + j0 + 16 * cb]);

        __syncthreads();
        {
            const ushort_t* g0 = (w == 0) ? Kh : Vth;
            const ushort_t* g1 = (w == 0) ? Kl : Vtl;
            ushort_t* lb0 = (w == 0) ? &Kls[0][0][0] : &Vls[0][0][0];
            ushort_t* lb1 = (w == 0) ? &Kls[1][0][0] : &Vls[1][0][0];
#pragma unroll
            for (int ch = 0; ch < 8; ++ch) {
                const int row = ch * 8 + (l >> 3);
                const int off8 = (((l & 7) ^ (row & 7)) << 3);
                const ushort_t* s0 =
                    (w == 0) ? g0 + ((size_t)((bh << 10) + j0 + row)) * 64 + off8
                             : g0 + ((size_t)((bh << 6) + row)) * 1024 + j0 + off8;
                const ushort_t* s1 =
                    (w == 0) ? g1 + ((size_t)((bh << 10) + j0 + row)) * 64 + off8
                             : g1 + ((size_t)((bh << 6) + row)) * 1024 + j0 + off8;
                gload16(s0, (char*)lb0 + ch * 1024);
                gload16(s1, (char*)lb1 + ch * 1024);
            }
        }
        __syncthreads();

        f32x4 s_[2][4];
#pragma unroll
        for (int cb = 0; cb < 4; ++cb) {
            const int row = 16 * cb + lm;
            const int sw = row & 7;
            const char* k0p = (const char*)&Kls[0][0][0] + row * 128;
            const char* k1p = (const char*)&Kls[1][0][0] + row * 128;
            const bf16x8 kh0 = *(const bf16x8*)(k0p + ((l4 + 0) ^ sw) * 16);
            const bf16x8 kh1 = *(const bf16x8*)(k0p + ((l4 + 4) ^ sw) * 16);
            const bf16x8 kl0 = *(const bf16x8*)(k1p + ((l4 + 0) ^ sw) * 16);
            const bf16x8 kl1 = *(const bf16x8*)(k1p + ((l4 + 4) ^ sw) * 16);
#pragma unroll
            for (int rg = 0; rg < 2; ++rg) {
                f32x4 a = (f32x4){0.f, 0.f, 0.f, 0.f};
                a = __builtin_amdgcn_mfma_f32_16x16x32_bf16(qh_[rg][0], kh0, a, 0, 0, 0);
                a = __builtin_amdgcn_mfma_f32_16x16x32_bf16(qh_[rg][1], kh1, a, 0, 0, 0);
                a = __builtin_amdgcn_mfma_f32_16x16x32_bf16(qh_[rg][0], kl0, a, 0, 0, 0);
                a = __builtin_amdgcn_mfma_f32_16x16x32_bf16(qh_[rg][1], kl1, a, 0, 0, 0);
                a = __builtin_amdgcn_mfma_f32_16x16x32_bf16(ql_[rg][0], kh0, a, 0, 0, 0);
                a = __builtin_amdgcn_mfma_f32_16x16x32_bf16(ql_[rg][1], kh1, a, 0, 0, 0);
                s_[rg][cb] = a;
            }
        }

#pragma unroll
        for (int rg = 0; rg < 2; ++rg) {
            uint_t* pw = &P32[w][rg][0][0];
#pragma unroll
            for (int cb = 0; cb < 4; ++cb)
#pragma unroll
                for (int r = 0; r < 4; ++r) {
                    const float p = __expf(s_[rg][cb][r] + bias_r[rg][cb][r]);
                    lsum[rg][r] += p;
                    const uint_t pu = __float_as_uint(p);
                    const ushort_t ph = (ushort_t)(pu >> 16);
                    const float rem = p - __uint_as_float(pu & 0xffff0000u);
                    const ushort_t pl2 = f2b(rem);
                    const uint_t packed = (uint_t)ph | ((uint_t)pl2 << 16);
                    const int rl = l4 * 4 + r;
                    const int col = (16 * cb + lm) ^ (l4 << 4);
                    pw[rl * 64 + col] = packed;
                }
        }

        bf16x8 pah[2][2], pal[2][2];
#pragma unroll
        for (int rg = 0; rg < 2; ++rg) {
            const uint_t* prow = &P32[w][rg][lm][0];
            const int key = ((lm >> 2) & 3) << 4;
#pragma unroll
            for (int ss = 0; ss < 2; ++ss) {
                const int col0 = ((l4 + 4 * ss) * 8) ^ key;
                const uint4 qa = *(const uint4*)&prow[col0];
                const uint4 qb = *(const uint4*)&prow[col0 + 4];
                union { uint_t u[4]; bf16x8 v; } hi, lo;
                hi.u[0] = __builtin_amdgcn_perm(qa.y, qa.x, 0x05040100u);
                hi.u[1] = __builtin_amdgcn_perm(qa.w, qa.z, 0x05040100u);
                hi.u[2] = __builtin_amdgcn_perm(qb.y, qb.x, 0x05040100u);
                hi.u[3] = __builtin_amdgcn_perm(qb.w, qb.z, 0x05040100u);
                lo.u[0] = __builtin_amdgcn_perm(qa.y, qa.x, 0x07060302u);
                lo.u[1] = __builtin_amdgcn_perm(qa.w, qa.z, 0x07060302u);
                lo.u[2] = __builtin_amdgcn_perm(qb.y, qb.x, 0x07060302u);
                lo.u[3] = __builtin_amdgcn_perm(qb.w, qb.z, 0x07060302u);
                pah[rg][ss] = hi.v;
                pal[rg][ss] = lo.v;
            }
        }

#pragma unroll
        for (int db = 0; db < 4; ++db) {
            const int vrow = 16 * db + lm;
            const int vw = vrow & 7;
            const char* v0p = (const char*)&Vls[0][0][0] + vrow * 128;
            const char* v1p = (const char*)&Vls[1][0][0] + vrow * 128;
            const bf16x8 vh0 = *(const bf16x8*)(v0p + ((l4 + 0) ^ vw) * 16);
            const bf16x8 vh1 = *(const bf16x8*)(v0p + ((l4 + 4) ^ vw) * 16);
            const bf16x8 vl0 = *(const bf16x8*)(v1p + ((l4 + 0) ^ vw) * 16);
            const bf16x8 vl1 = *(const bf16x8*)(v1p + ((l4 + 4) ^ vw) * 16);
#pragma unroll
            for (int rg = 0; rg < 2; ++rg) {
                f32x4 a = o_[rg][db];
                a = __builtin_amdgcn_mfma_f32_16x16x32_bf16(pah[rg][0], vh0, a, 0, 0, 0);
                a = __builtin_amdgcn_mfma_f32_16x16x32_bf16(pah[rg][1], vh1, a, 0, 0, 0);
                a = __builtin_amdgcn_mfma_f32_16x16x32_bf16(pah[rg][0], vl0, a, 0, 0, 0);
                a = __builtin_amdgcn_mfma_f32_16x16x32_bf16(pah[rg][1], vl1, a, 0, 0, 0);
                a = __builtin_amdgcn_mfma_f32_16x16x32_bf16(pal[rg][0], vh0, a, 0, 0, 0);
                a = __builtin_amdgcn_mfma_f32_16x16x32_bf16(pal[rg][1], vh1, a, 0, 0, 0);
                o_[rg][db] = a;
            }
        }
    }

#pragma unroll
    for (int rg = 0; rg < 2; ++rg)
#pragma unroll
        for (int r = 0; r < 4; ++r) {
            float lf = lsum[rg][r];
            lf += __shfl_xor(lf, 1);
            lf += __shfl_xor(lf, 2);
            lf += __shfl_xor(lf, 4);
            lf += __shfl_xor(lf, 8);
            const float inv = 1.f / lf;
            const int row = (b << 10) + rowbase + rg * 16 + l4 * 4 + r;
            ushort_t* rowp = A2 + (size_t)row * 1536;
#pragma unroll
            for (int db = 0; db < 4; ++db) {
                const float val = o_[rg][db][r] * inv;
                const ushort_t hi = f2b(val);
                const ushort_t lo = f2b(val - b2f(hi));
                const int c = (h << 6) + 16 * db + lm;
                rowp[c] = hi;
                rowp[768 + c] = lo;
            }
        }
}

extern "C" void kernel_launch(void* const* d_in, const int* in_sizes, int n_in,
                              void* d_out, int out_size, void* d_ws, size_t ws_size,
                              hipStream_t stream) {
    const float* x   = (const float*)d_in[0];
    const float* pos = (const float*)d_in[1];
    const float* Wq  = (const float*)d_in[2];
    const float* bq  = (const float*)d_in[3];
    const float* Wk  = (const float*)d_in[4];
    const float* bk  = (const float*)d_in[5];
    const float* Wv  = (const float*)d_in[6];
    const float* bv  = (const float*)d_in[7];
    const float* Wo  = (const float*)d_in[8];
    const float* bo  = (const float*)d_in[9];
    const float* W1  = (const float*)d_in[10];
    const float* b1  = (const float*)d_in[11];
    const float* W2  = (const float*)d_in[12];
    const float* b2  = (const float*)d_in[13];
    float* out = (float*)d_out;

    ushort_t* Qhb = (ushort_t*)d_ws;          // [48][1024][64]
    ushort_t* Qlb = Qhb + 3145728;
    ushort_t* Khb = Qlb + 3145728;
    ushort_t* Klb = Khb + 3145728;
    ushort_t* Vth = Klb + 3145728;            // [48][64][1024]
    ushort_t* Vtl = Vth + 3145728;
    ushort_t* A2  = Vtl + 3145728;            // [4096][1536]
    ushort_t* W2b = A2 + 6291456;             // [2304][1536]
    __half* BiasH = (__half*)(W2b + 3538944); // [48][1024][1024]
    float* W2t    = (float*)(BiasH + 50331648); // [12][32]

    split_hi_lo<<<3072, 256, 0, stream>>>(x, A2);
    split_wT<<<dim3(12, 12), 256, 0, stream>>>(Wq, W2b, 0);
    split_wT<<<dim3(12, 12), 256, 0, stream>>>(Wk, W2b, 768);
    split_wT<<<dim3(12, 12), 256, 0, stream>>>(Wv, W2b, 1536);
    prep_w2t<<<1, 384, 0, stream>>>(W2, W2t);

    mfma_gemm<1><<<dim3(18, 32), 256, 0, stream>>>(
        A2, W2b, bq, bk, bv, Qhb, Qlb, Khb, Klb, Vth, Vtl, nullptr);

    bias_mlp<<<dim3(1024, 4, 2), 256, 0, stream>>>(pos, W1, b1, W2t, b2, BiasH);

    attn_mfma<<<768, 128, 0, stream>>>(Qhb, Qlb, Khb, Klb, Vth, Vtl, BiasH, A2);

    split_wT<<<dim3(12, 12), 256, 0, stream>>>(Wo, W2b, 0);
    mfma_gemm<0><<<dim3(6, 32), 256, 0, stream>>>(
        A2, W2b, bo, nullptr, nullptr, nullptr, nullptr, nullptr, nullptr, nullptr,
        nullptr, out);
}